// Round 10
// baseline (1179.303 us; speedup 1.0000x reference)
//
#include <hip/hip_runtime.h>
#include <hip/hip_cooperative_groups.h>
#include <math.h>

namespace cg = cooperative_groups;

#define BATCH 2048
#define CH 512
#define N_COARSE 256
#define F_FINE 256
#define K_TOP 4
#define OUT_STRIDE 65537  // 1 + N*F

typedef unsigned short ushort_t;
typedef __bf16 bf16x8 __attribute__((ext_vector_type(8)));
typedef float f32x4 __attribute__((ext_vector_type(4)));

__device__ __forceinline__ float gelu_tanh(float x) {
    float x3 = x * x * x;
    float t = tanhf(0.7978845608028654f * (x + 0.044715f * x3));
    return 0.5f * x * (1.0f + t);
}

__device__ __forceinline__ ushort_t f2bf(float f) {
    unsigned u = __float_as_uint(f);
    unsigned r = (u + 0x7FFF + ((u >> 16) & 1)) >> 16;
    return (ushort_t)r;
}
__device__ __forceinline__ float bf2f(ushort_t h) {
    return __uint_as_float(((unsigned)h) << 16);
}

struct Params {
    const float *x, *in_g, *in_b, *nop_w, *nop_b;
    const float *c_w1, *c_b1, *c_w2, *c_b2, *c_w3, *c_b3;
    const float *emb, *emb_g, *emb_b;
    const float *f_w1, *f_b1, *f_w2, *f_b2, *f_w3, *f_b3;
    float *coarse, *fine, *out, *cvals;
    ushort_t *xnsp, *h1sp, *h2sp, *e_bf, *fh1_bf, *fh2_bf;
    ushort_t *wt1, *wt2, *wt3, *cwt1, *cwt2, *cwt3;
    int *idxb;
};

// ---------------- prep unit: u<896 fine convT; u<1536 coarse convT hi/lo; else LN+no_op ----
__device__ __forceinline__ void prep_unit(char* smem, int u, int t, const Params& p) {
    if (u < 1536) {
        float (*s)[33] = (float(*)[33])smem;
        const float* W; ushort_t* Wt; int Kd, Nd, gx, gy; bool split;
        if (u < 512)       { W=p.f_w1; Wt=p.wt1; Kd=1024; Nd=512; gx=u&15; gy=u>>4; split=false; }
        else if (u < 768)  { int v=u-512;  W=p.f_w2; Wt=p.wt2; Kd=512; Nd=512; gx=v&15; gy=v>>4; split=false; }
        else if (u < 896)  { int v=u-768;  W=p.f_w3; Wt=p.wt3; Kd=512; Nd=256; gx=v&7;  gy=v>>3; split=false; }
        else if (u < 1152) { int v=u-896;  W=p.c_w1; Wt=p.cwt1; Kd=512; Nd=512; gx=v&15; gy=v>>4; split=true; }
        else if (u < 1408) { int v=u-1152; W=p.c_w2; Wt=p.cwt2; Kd=512; Nd=512; gx=v&15; gy=v>>4; split=true; }
        else               { int v=u-1408; W=p.c_w3; Wt=p.cwt3; Kd=512; Nd=256; gx=v&7;  gy=v>>3; split=true; }
        int tx = t & 31, ty = t >> 5;
        int n0 = gx * 32, k0 = gy * 32;
        #pragma unroll
        for (int i = 0; i < 4; ++i) {
            int r = ty + i * 8;
            s[r][tx] = W[(size_t)(k0 + r) * Nd + n0 + tx];
        }
        __syncthreads();
        if (!split) {
            #pragma unroll
            for (int i = 0; i < 4; ++i) {
                int r = ty + i * 8;
                Wt[(size_t)(n0 + r) * Kd + k0 + tx] = f2bf(s[tx][r]);
            }
        } else {
            #pragma unroll
            for (int i = 0; i < 4; ++i) {
                int r = ty + i * 8;
                float v = s[tx][r];
                ushort_t h = f2bf(v);
                Wt[(size_t)(n0 + r) * 1024 + k0 + tx] = h;
                Wt[(size_t)(n0 + r) * 1024 + 512 + k0 + tx] = f2bf(v - bf2f(h));
            }
        }
    } else {
        float* red = (float*)smem;
        int row = u - 1536;
        int lane = t & 63, wave = t >> 6;
        const float* xr = p.x + (size_t)row * CH;
        float v0 = xr[t], v1 = xr[t + 256];
        float sm = v0 + v1, ss = v0 * v0 + v1 * v1;
        #pragma unroll
        for (int off = 32; off; off >>= 1) { sm += __shfl_xor(sm, off); ss += __shfl_xor(ss, off); }
        if (lane == 0) { red[wave] = sm; red[4 + wave] = ss; }
        __syncthreads();
        sm = red[0] + red[1] + red[2] + red[3];
        ss = red[4] + red[5] + red[6] + red[7];
        float mean = sm * (1.0f / CH);
        float var = ss * (1.0f / CH) - mean * mean;
        float rsq = rsqrtf(var + 1e-5f);
        float xn0 = (v0 - mean) * rsq * p.in_g[t] + p.in_b[t];
        float xn1 = (v1 - mean) * rsq * p.in_g[t + 256] + p.in_b[t + 256];
        ushort_t* xr2 = p.xnsp + (size_t)row * 1024;
        ushort_t h0 = f2bf(xn0), h1v = f2bf(xn1);
        xr2[t] = h0; xr2[t + 256] = h1v;
        xr2[512 + t] = f2bf(xn0 - bf2f(h0));
        xr2[512 + t + 256] = f2bf(xn1 - bf2f(h1v));
        float d = xn0 * p.nop_w[t] + xn1 * p.nop_w[t + 256];
        #pragma unroll
        for (int off = 32; off; off >>= 1) d += __shfl_xor(d, off);
        __syncthreads();
        if (lane == 0) red[wave] = d;
        __syncthreads();
        if (t == 0) p.out[(size_t)row * OUT_STRIDE] = red[0] + red[1] + red[2] + red[3] + p.nop_b[0];
    }
}

// ---------------- bf16 MFMA GEMM tile (device), BK=32, reg-prefetch + LDS dbuf ----------------
// MODE 0: A1 row-major stride Ktot.  MODE 1: concat hi(xnsp)/e.  MODE 2: 3-term split K=1536.
// OUTM 0: bf16+gelu stride Nd. OUTM 1: split hi/lo bf16+gelu stride 1024.
// OUTM 2: f32. OUTM 3: f32 = cvals + log_softmax (NT==Nd==256, MT==64).
template<int MODE, int MT, int NT, int OUTM>
__device__ __forceinline__ void mfma_tile(
    char* smem, int t, int n0, int m0,
    const ushort_t* __restrict__ A1, const ushort_t* __restrict__ A2,
    const ushort_t* __restrict__ Wt, const float* __restrict__ bias,
    const float* __restrict__ cvals, void* __restrict__ Cout, int Nd, int Ktot)
{
    constexpr int AI = MT / 64, BI = NT / 64;
    constexpr int FI = MT / 32, FJ = NT / 32;
    ushort_t* As = (ushort_t*)smem;
    ushort_t* Bs = (ushort_t*)(smem + MT * 128);
    float* mxs = (float*)(smem + (MT + NT) * 128);
    float* ses = mxs + 128;
    int wave = t >> 6, lane = t & 63;
    int wm = (wave & 1) * (MT / 2), wn = (wave >> 1) * (NT / 2);
    int lr = lane & 15, quad = lane >> 4;

    f32x4 acc[FI][FJ] = {};
    float4 aReg[AI], bReg[BI];

    auto loadAB = [&](int k0) {
        int aoff = (MODE == 2) ? ((k0 >= 1024) ? k0 - 512 : (k0 & 511)) : k0;
        int woff = (MODE == 2) ? ((k0 >= 1024) ? k0 - 1024 : k0) : k0;
        #pragma unroll
        for (int i = 0; i < AI; ++i) {
            int c = i * 256 + t, r = c >> 2, q = (c & 3) * 8;
            int gr = m0 + r;
            const ushort_t* ap;
            if (MODE == 1)      ap = (k0 < 512) ? A1 + (size_t)(gr >> 2) * 1024 + k0 + q
                                                : A2 + (size_t)gr * 512 + (k0 - 512) + q;
            else if (MODE == 2) ap = A1 + (size_t)gr * 1024 + aoff + q;
            else                ap = A1 + (size_t)gr * Ktot + k0 + q;
            aReg[i] = *(const float4*)ap;
        }
        #pragma unroll
        for (int i = 0; i < BI; ++i) {
            int c = i * 256 + t, r = c >> 2, q = (c & 3) * 8;
            size_t wstride = (MODE == 2) ? 1024 : (size_t)Ktot;
            bReg[i] = *(const float4*)(Wt + (size_t)(n0 + r) * wstride + woff + q);
        }
    };
    auto storeAB = [&](int p) {
        #pragma unroll
        for (int i = 0; i < AI; ++i) { int c = i * 256 + t; *(float4*)&As[p * MT * 32 + c * 8] = aReg[i]; }
        #pragma unroll
        for (int i = 0; i < BI; ++i) { int c = i * 256 + t; *(float4*)&Bs[p * NT * 32 + c * 8] = bReg[i]; }
    };

    loadAB(0);
    storeAB(0);
    int steps = Ktot >> 5;
    int p = 0;
    for (int s = 0; s < steps; ++s) {
        __syncthreads();
        if (s + 1 < steps) loadAB((s + 1) * 32);
        bf16x8 af[FI], bfr[FJ];
        #pragma unroll
        for (int i = 0; i < FI; ++i)
            af[i] = *(const bf16x8*)&As[p * MT * 32 + (wm + i * 16 + lr) * 32 + quad * 8];
        #pragma unroll
        for (int j = 0; j < FJ; ++j)
            bfr[j] = *(const bf16x8*)&Bs[p * NT * 32 + (wn + j * 16 + lr) * 32 + quad * 8];
        #pragma unroll
        for (int i = 0; i < FI; ++i)
            #pragma unroll
            for (int j = 0; j < FJ; ++j)
                acc[i][j] = __builtin_amdgcn_mfma_f32_16x16x32_bf16(af[i], bfr[j], acc[i][j], 0, 0, 0);
        if (s + 1 < steps) storeAB(p ^ 1);
        p ^= 1;
    }

    if (OUTM == 3) {
        float bv[FJ];
        #pragma unroll
        for (int j = 0; j < FJ; ++j) bv[j] = bias[wn + j * 16 + lr];
        int half = wave >> 1;
        float rmx[FI][4];
        #pragma unroll
        for (int i = 0; i < FI; ++i)
            #pragma unroll
            for (int r = 0; r < 4; ++r) {
                float m = -1e30f;
                #pragma unroll
                for (int j = 0; j < FJ; ++j) m = fmaxf(m, acc[i][j][r] + bv[j]);
                #pragma unroll
                for (int mk = 1; mk < 16; mk <<= 1) m = fmaxf(m, __shfl_xor(m, mk));
                if (lr == 0) mxs[(wm + i * 16 + quad * 4 + r) * 2 + half] = m;
            }
        __syncthreads();
        #pragma unroll
        for (int i = 0; i < FI; ++i)
            #pragma unroll
            for (int r = 0; r < 4; ++r) {
                int rl = wm + i * 16 + quad * 4 + r;
                rmx[i][r] = fmaxf(mxs[rl * 2], mxs[rl * 2 + 1]);
            }
        #pragma unroll
        for (int i = 0; i < FI; ++i)
            #pragma unroll
            for (int r = 0; r < 4; ++r) {
                float sv = 0.f;
                #pragma unroll
                for (int j = 0; j < FJ; ++j) sv += expf(acc[i][j][r] + bv[j] - rmx[i][r]);
                #pragma unroll
                for (int mk = 1; mk < 16; mk <<= 1) sv += __shfl_xor(sv, mk);
                if (lr == 0) ses[(wm + i * 16 + quad * 4 + r) * 2 + half] = sv;
            }
        __syncthreads();
        float* outp = (float*)Cout;
        #pragma unroll
        for (int i = 0; i < FI; ++i)
            #pragma unroll
            for (int r = 0; r < 4; ++r) {
                int rl = wm + i * 16 + quad * 4 + r;
                float se = ses[rl * 2] + ses[rl * 2 + 1];
                float addc = cvals[m0 + rl] - rmx[i][r] - logf(se);
                #pragma unroll
                for (int j = 0; j < FJ; ++j)
                    outp[(size_t)(m0 + rl) * Nd + wn + j * 16 + lr] = acc[i][j][r] + bv[j] + addc;
            }
    } else {
        #pragma unroll
        for (int j = 0; j < FJ; ++j) {
            int col = n0 + wn + j * 16 + lr;
            float bvv = bias[col];
            #pragma unroll
            for (int i = 0; i < FI; ++i) {
                #pragma unroll
                for (int r = 0; r < 4; ++r) {
                    int row = m0 + wm + i * 16 + quad * 4 + r;
                    float val = acc[i][j][r] + bvv;
                    if (OUTM == 0) {
                        ((ushort_t*)Cout)[(size_t)row * Nd + col] = f2bf(gelu_tanh(val));
                    } else if (OUTM == 1) {
                        float gv = gelu_tanh(val);
                        ushort_t h = f2bf(gv);
                        ((ushort_t*)Cout)[(size_t)row * 1024 + col] = h;
                        ((ushort_t*)Cout)[(size_t)row * 1024 + 512 + col] = f2bf(gv - bf2f(h));
                    } else {
                        ((float*)Cout)[(size_t)row * Nd + col] = val;
                    }
                }
            }
        }
    }
}

// ---------------- top-4 + emb gather+LN for one batch row (block-level) ----------------
__device__ __forceinline__ void topk_embln_block(char* smem, int brow, int t, const Params& p) {
    int wave = t >> 6, lane = t & 63;
    int* sidx = (int*)smem;
    if (wave == 0) {
        const float* cr = p.coarse + (size_t)brow * N_COARSE;
        float v[4]; int id[4];
        #pragma unroll
        for (int j = 0; j < 4; ++j) { v[j] = cr[lane + 64 * j]; id[j] = lane + 64 * j; }
        #pragma unroll
        for (int r = 0; r < K_TOP; ++r) {
            float bv = v[0]; int bi = id[0];
            #pragma unroll
            for (int j = 1; j < 4; ++j)
                if (v[j] > bv || (v[j] == bv && id[j] < bi)) { bv = v[j]; bi = id[j]; }
            #pragma unroll
            for (int off = 32; off; off >>= 1) {
                float ov = __shfl_xor(bv, off); int oi = __shfl_xor(bi, off);
                if (ov > bv || (ov == bv && oi < bi)) { bv = ov; bi = oi; }
            }
            if ((bi & 63) == lane) v[bi >> 6] = -INFINITY;
            if (lane == 0) {
                sidx[r] = bi;
                p.idxb[brow * K_TOP + r] = bi;
                p.cvals[brow * K_TOP + r] = bv;
            }
        }
    }
    __syncthreads();
    int n = sidx[wave];
    const float* er = p.emb + (size_t)n * CH + lane * 8;
    float4 u0 = *(const float4*)er;
    float4 u1 = *(const float4*)(er + 4);
    float s  = u0.x + u0.y + u0.z + u0.w + u1.x + u1.y + u1.z + u1.w;
    float ss = u0.x * u0.x + u0.y * u0.y + u0.z * u0.z + u0.w * u0.w
             + u1.x * u1.x + u1.y * u1.y + u1.z * u1.z + u1.w * u1.w;
    #pragma unroll
    for (int off = 32; off; off >>= 1) { s += __shfl_xor(s, off); ss += __shfl_xor(ss, off); }
    float mean = s * (1.0f / CH);
    float var = ss * (1.0f / CH) - mean * mean;
    float rsq = rsqrtf(var + 1e-5f);
    float4 g0 = *(const float4*)(p.emb_g + lane * 8), g1 = *(const float4*)(p.emb_g + lane * 8 + 4);
    float4 b0 = *(const float4*)(p.emb_b + lane * 8), b1 = *(const float4*)(p.emb_b + lane * 8 + 4);
    uint4 pk;
    pk.x = (unsigned)f2bf((u0.x - mean) * rsq * g0.x + b0.x) |
           ((unsigned)f2bf((u0.y - mean) * rsq * g0.y + b0.y) << 16);
    pk.y = (unsigned)f2bf((u0.z - mean) * rsq * g0.z + b0.z) |
           ((unsigned)f2bf((u0.w - mean) * rsq * g0.w + b0.w) << 16);
    pk.z = (unsigned)f2bf((u1.x - mean) * rsq * g1.x + b1.x) |
           ((unsigned)f2bf((u1.y - mean) * rsq * g1.y + b1.y) << 16);
    pk.w = (unsigned)f2bf((u1.z - mean) * rsq * g1.z + b1.z) |
           ((unsigned)f2bf((u1.w - mean) * rsq * g1.w + b1.w) << 16);
    *(uint4*)(p.e_bf + (size_t)(brow * K_TOP + wave) * CH + lane * 8) = pk;
}

// ---------------- scatter one 4096-elem chunk (b, cx) ----------------
__device__ __forceinline__ void scatter_unit(int b, int cx, int t, const Params& p) {
    const float LOG_F = 5.545177444479562f;
    int4 ii = *(const int4*)&p.idxb[b * 4];
    size_t rowb = (size_t)b * OUT_STRIDE + 1;
    #pragma unroll
    for (int q = 0; q < 4; ++q) {
        int o = cx * 4096 + q * 1024 + t * 4;
        int c0 = o >> 12, f0 = (o >> 8) & 15, c1 = (o >> 4) & 15, f1 = o & 15;
        int n = c0 * 16 + c1;
        int f = f0 * 16 + f1;
        int k = -1;
        if (n == ii.x) k = 0; else if (n == ii.y) k = 1; else if (n == ii.z) k = 2; else if (n == ii.w) k = 3;
        float r0, r1, r2, r3;
        if (k >= 0) {
            float4 u = *(const float4*)(p.fine + ((size_t)(b * 4 + k)) * F_FINE + f);
            r0 = u.x; r1 = u.y; r2 = u.z; r3 = u.w;
        } else {
            float base = p.coarse[(size_t)b * N_COARSE + n] - LOG_F;
            r0 = r1 = r2 = r3 = base;
        }
        float* op = p.out + rowb + o;
        __builtin_nontemporal_store(r0, op + 0);
        __builtin_nontemporal_store(r1, op + 1);
        __builtin_nontemporal_store(r2, op + 2);
        __builtin_nontemporal_store(r3, op + 3);
    }
}

// ========== cooperative mega-kernel: 512 blocks x 256 threads, NO scatter ==========
// __launch_bounds__(256): without it hipcc targets 1024-thread blocks -> 64 VGPR cap ->
// MFMA accumulators spill to scratch (R8/R9: VGPR_Count=64, MfmaUtil<2%, 3x slowdown).
__global__ __launch_bounds__(256) void mega_kernel(Params p) {
    __shared__ __attribute__((aligned(16))) char smem[41984];
    cg::grid_group grid = cg::this_grid();
    int blk = blockIdx.x, t = threadIdx.x;

    for (int u = blk; u < 3584; u += 512) { prep_unit(smem, u, t, p); __syncthreads(); }
    grid.sync();
    if (blk < 256)
        mfma_tile<2, 64, 64, 1>(smem, t, (blk & 7) * 64, (blk >> 3) * 64,
                                p.xnsp, nullptr, p.cwt1, p.c_b1, nullptr, p.h1sp, 512, 1536);
    grid.sync();
    if (blk < 256)
        mfma_tile<2, 64, 64, 1>(smem, t, (blk & 7) * 64, (blk >> 3) * 64,
                                p.h1sp, nullptr, p.cwt2, p.c_b2, nullptr, p.h2sp, 512, 1536);
    grid.sync();
    if (blk < 128)
        mfma_tile<2, 64, 64, 2>(smem, t, (blk & 3) * 64, (blk >> 2) * 64,
                                p.h2sp, nullptr, p.cwt3, p.c_b3, nullptr, p.coarse, 256, 1536);
    grid.sync();
    for (int it = 0; it < 4; ++it) { topk_embln_block(smem, blk + it * 512, t, p); __syncthreads(); }
    grid.sync();
    mfma_tile<1, 64, 128, 0>(smem, t, (blk & 3) * 128, (blk >> 2) * 64,
                             p.xnsp, p.e_bf, p.wt1, p.f_b1, nullptr, p.fh1_bf, 512, 1024);
    grid.sync();
    mfma_tile<0, 64, 128, 0>(smem, t, (blk & 3) * 128, (blk >> 2) * 64,
                             p.fh1_bf, nullptr, p.wt2, p.f_b2, nullptr, p.fh2_bf, 512, 512);
    grid.sync();
    if (blk < 128)
        mfma_tile<0, 64, 256, 3>(smem, t, 0, blk * 64,
                                 p.fh2_bf, nullptr, p.wt3, p.f_b3, p.cvals, p.fine, 256, 512);
}

// ================= standalone kernels (R7-proven structure) =================
__global__ __launch_bounds__(256) void prep_kernel(Params p) {
    __shared__ __attribute__((aligned(16))) char smem[4224];
    prep_unit(smem, blockIdx.x, threadIdx.x, p);
}

template<int MODE, int MT, int NT, int OUTM>
__global__ __launch_bounds__(256) void mfma_gemm_kernel(
    const ushort_t* __restrict__ A1, const ushort_t* __restrict__ A2,
    const ushort_t* __restrict__ Wt, const float* __restrict__ bias,
    const float* __restrict__ cvals, void* __restrict__ Cout, int Nd, int Ktot)
{
    constexpr int SB = (MT + NT) * 128 + (OUTM == 3 ? 1024 : 0);
    __shared__ __attribute__((aligned(16))) char smem[SB];
    mfma_tile<MODE, MT, NT, OUTM>(smem, threadIdx.x, blockIdx.x * NT, blockIdx.y * MT,
                                  A1, A2, Wt, bias, cvals, Cout, Nd, Ktot);
}

__global__ __launch_bounds__(256) void topk_embln_kernel(Params p) {
    __shared__ __attribute__((aligned(16))) char smem[16];
    topk_embln_block(smem, blockIdx.x, threadIdx.x, p);
}

__global__ __launch_bounds__(256) void scatter_kernel(Params p) {
    scatter_unit(blockIdx.y, blockIdx.x, threadIdx.x, p);
}

extern "C" void kernel_launch(void* const* d_in, const int* in_sizes, int n_in,
                              void* d_out, int out_size, void* d_ws, size_t ws_size,
                              hipStream_t stream) {
    Params prm;
    prm.x     = (const float*)d_in[0];
    prm.in_g  = (const float*)d_in[1];
    prm.in_b  = (const float*)d_in[2];
    prm.nop_w = (const float*)d_in[3];
    prm.nop_b = (const float*)d_in[4];
    prm.c_w1  = (const float*)d_in[5];
    prm.c_b1  = (const float*)d_in[6];
    prm.c_w2  = (const float*)d_in[7];
    prm.c_b2  = (const float*)d_in[8];
    prm.c_w3  = (const float*)d_in[9];
    prm.c_b3  = (const float*)d_in[10];
    prm.emb   = (const float*)d_in[11];
    prm.emb_g = (const float*)d_in[12];
    prm.emb_b = (const float*)d_in[13];
    prm.f_w1  = (const float*)d_in[14];
    prm.f_b1  = (const float*)d_in[15];
    prm.f_w2  = (const float*)d_in[16];
    prm.f_b2  = (const float*)d_in[17];
    prm.f_w3  = (const float*)d_in[18];
    prm.f_b3  = (const float*)d_in[19];

    float* ws = (float*)d_ws;
    prm.coarse  = ws;                             // 2048*256 f32
    prm.fine    = prm.coarse + 524288;            // 8192*256 f32
    prm.xnsp    = (ushort_t*)(prm.fine + 2097152);  // 2048*1024 bf16 [hi|lo]
    prm.h1sp    = prm.xnsp + 2097152;             // 2048*1024
    prm.h2sp    = prm.h1sp + 2097152;             // 2048*1024
    prm.e_bf    = prm.h2sp + 2097152;             // 8192*512
    prm.fh1_bf  = prm.e_bf + 4194304;             // 8192*512
    prm.fh2_bf  = prm.fh1_bf + 4194304;           // 8192*512
    prm.wt1     = prm.fh2_bf + 4194304;           // 512*1024
    prm.wt2     = prm.wt1 + 524288;               // 512*512
    prm.wt3     = prm.wt2 + 262144;               // 256*512
    prm.cwt1    = prm.wt3 + 131072;               // 512*1024
    prm.cwt2    = prm.cwt1 + 524288;              // 512*1024
    prm.cwt3    = prm.cwt2 + 524288;              // 256*1024
    prm.idxb    = (int*)(prm.cwt3 + 262144);      // 8192
    prm.cvals   = (float*)(prm.idxb + 8192);      // 8192
    prm.out     = (float*)d_out;

    void* kargs[] = { (void*)&prm };
    hipError_t err = hipLaunchCooperativeKernel((const void*)mega_kernel, dim3(512), dim3(256),
                                                kargs, 0, stream);
    if (err != hipSuccess) {
        (void)hipGetLastError();  // clear sticky error; run proven 8-dispatch chain
        prep_kernel<<<3584, 256, 0, stream>>>(prm);
        mfma_gemm_kernel<2, 64, 64, 1><<<dim3(8, 32), 256, 0, stream>>>(
            prm.xnsp, nullptr, prm.cwt1, prm.c_b1, nullptr, prm.h1sp, 512, 1536);
        mfma_gemm_kernel<2, 64, 64, 1><<<dim3(8, 32), 256, 0, stream>>>(
            prm.h1sp, nullptr, prm.cwt2, prm.c_b2, nullptr, prm.h2sp, 512, 1536);
        mfma_gemm_kernel<2, 64, 64, 2><<<dim3(4, 32), 256, 0, stream>>>(
            prm.h2sp, nullptr, prm.cwt3, prm.c_b3, nullptr, prm.coarse, 256, 1536);
        topk_embln_kernel<<<BATCH, 256, 0, stream>>>(prm);
        mfma_gemm_kernel<1, 64, 128, 0><<<dim3(4, 128), 256, 0, stream>>>(
            prm.xnsp, prm.e_bf, prm.wt1, prm.f_b1, nullptr, prm.fh1_bf, 512, 1024);
        mfma_gemm_kernel<0, 64, 128, 0><<<dim3(4, 128), 256, 0, stream>>>(
            prm.fh1_bf, nullptr, prm.wt2, prm.f_b2, nullptr, prm.fh2_bf, 512, 512);
        mfma_gemm_kernel<0, 64, 256, 3><<<dim3(1, 128), 256, 0, stream>>>(
            prm.fh2_bf, nullptr, prm.wt3, prm.f_b3, prm.cvals, prm.fine, 256, 512);
    }
    // scatter is always a wide standalone launch (write-BW needs full occupancy)
    scatter_kernel<<<dim3(16, BATCH), 256, 0, stream>>>(prm);
}

// Round 11
// 730.025 us; speedup vs baseline: 1.6154x; 1.6154x over previous
//
#include <hip/hip_runtime.h>
#include <math.h>

#define BATCH 2048
#define CH 512
#define N_COARSE 256
#define F_FINE 256
#define K_TOP 4
#define OUT_STRIDE 65537  // 1 + N*F

typedef unsigned short ushort_t;
typedef __bf16 bf16x8 __attribute__((ext_vector_type(8)));
typedef float f32x4 __attribute__((ext_vector_type(4)));

__device__ __forceinline__ float gelu_tanh(float x) {
    float x3 = x * x * x;
    float t = tanhf(0.7978845608028654f * (x + 0.044715f * x3));
    return 0.5f * x * (1.0f + t);
}

__device__ __forceinline__ ushort_t f2bf(float f) {
    unsigned u = __float_as_uint(f);
    unsigned r = (u + 0x7FFF + ((u >> 16) & 1)) >> 16;
    return (ushort_t)r;
}
__device__ __forceinline__ float bf2f(ushort_t h) {
    return __uint_as_float(((unsigned)h) << 16);
}

struct Params {
    const float *x, *in_g, *in_b, *nop_w, *nop_b;
    const float *c_w1, *c_b1, *c_w2, *c_b2, *c_w3, *c_b3;
    const float *emb, *emb_g, *emb_b;
    const float *f_w1, *f_b1, *f_w2, *f_b2, *f_w3, *f_b3;
    float *coarse, *fine, *out, *cvals;
    ushort_t *xnsp, *h1sp, *h2sp, *e_bf, *fh1_bf, *fh2_bf;
    ushort_t *wt1, *wt2, *wt3, *cwt1, *cwt2, *cwt3;
    int *idxb;
};

// ---------------- prep: u<896 fine convT; u<1536 coarse convT hi/lo; else LN+no_op ----
__global__ __launch_bounds__(256) void prep_kernel(Params p) {
    __shared__ float s[32][33];
    int u = blockIdx.x, t = threadIdx.x;
    if (u < 1536) {
        const float* W; ushort_t* Wt; int Kd, Nd, gx, gy; bool split;
        if (u < 512)       { W=p.f_w1; Wt=p.wt1; Kd=1024; Nd=512; gx=u&15; gy=u>>4; split=false; }
        else if (u < 768)  { int v=u-512;  W=p.f_w2; Wt=p.wt2; Kd=512; Nd=512; gx=v&15; gy=v>>4; split=false; }
        else if (u < 896)  { int v=u-768;  W=p.f_w3; Wt=p.wt3; Kd=512; Nd=256; gx=v&7;  gy=v>>3; split=false; }
        else if (u < 1152) { int v=u-896;  W=p.c_w1; Wt=p.cwt1; Kd=512; Nd=512; gx=v&15; gy=v>>4; split=true; }
        else if (u < 1408) { int v=u-1152; W=p.c_w2; Wt=p.cwt2; Kd=512; Nd=512; gx=v&15; gy=v>>4; split=true; }
        else               { int v=u-1408; W=p.c_w3; Wt=p.cwt3; Kd=512; Nd=256; gx=v&7;  gy=v>>3; split=true; }
        int tx = t & 31, ty = t >> 5;
        int n0 = gx * 32, k0 = gy * 32;
        #pragma unroll
        for (int i = 0; i < 4; ++i) {
            int r = ty + i * 8;
            s[r][tx] = W[(size_t)(k0 + r) * Nd + n0 + tx];
        }
        __syncthreads();
        if (!split) {
            #pragma unroll
            for (int i = 0; i < 4; ++i) {
                int r = ty + i * 8;
                Wt[(size_t)(n0 + r) * Kd + k0 + tx] = f2bf(s[tx][r]);
            }
        } else {
            #pragma unroll
            for (int i = 0; i < 4; ++i) {
                int r = ty + i * 8;
                float v = s[tx][r];
                ushort_t h = f2bf(v);
                Wt[(size_t)(n0 + r) * 1024 + k0 + tx] = h;
                Wt[(size_t)(n0 + r) * 1024 + 512 + k0 + tx] = f2bf(v - bf2f(h));
            }
        }
    } else {
        float* red = &s[0][0];
        int row = u - 1536;
        int lane = t & 63, wave = t >> 6;
        const float* xr = p.x + (size_t)row * CH;
        float v0 = xr[t], v1 = xr[t + 256];
        float sm = v0 + v1, ss = v0 * v0 + v1 * v1;
        #pragma unroll
        for (int off = 32; off; off >>= 1) { sm += __shfl_xor(sm, off); ss += __shfl_xor(ss, off); }
        if (lane == 0) { red[wave] = sm; red[4 + wave] = ss; }
        __syncthreads();
        sm = red[0] + red[1] + red[2] + red[3];
        ss = red[4] + red[5] + red[6] + red[7];
        float mean = sm * (1.0f / CH);
        float var = ss * (1.0f / CH) - mean * mean;
        float rsq = rsqrtf(var + 1e-5f);
        float xn0 = (v0 - mean) * rsq * p.in_g[t] + p.in_b[t];
        float xn1 = (v1 - mean) * rsq * p.in_g[t + 256] + p.in_b[t + 256];
        ushort_t* xr2 = p.xnsp + (size_t)row * 1024;
        ushort_t h0 = f2bf(xn0), h1v = f2bf(xn1);
        xr2[t] = h0; xr2[t + 256] = h1v;
        xr2[512 + t] = f2bf(xn0 - bf2f(h0));
        xr2[512 + t + 256] = f2bf(xn1 - bf2f(h1v));
        float d = xn0 * p.nop_w[t] + xn1 * p.nop_w[t + 256];
        #pragma unroll
        for (int off = 32; off; off >>= 1) d += __shfl_xor(d, off);
        __syncthreads();
        if (lane == 0) red[wave] = d;
        __syncthreads();
        if (t == 0) p.out[(size_t)row * OUT_STRIDE] = red[0] + red[1] + red[2] + red[3] + p.nop_b[0];
    }
}

// ---------------- bf16 MFMA GEMM, MTxNT tile, BK=32, reg-prefetch + LDS dbuf ----------------
// MODE 0: A1 row-major stride Ktot.  MODE 1: concat hi(xnsp)/e.  MODE 2: 3-term split K=1536.
// OUTM 0: bf16+gelu stride Nd. OUTM 1: split hi/lo bf16+gelu stride 1024.
// OUTM 2: f32. OUTM 3: f32 = cvals + log_softmax (NT==Nd==256, MT==64).
template<int MODE, int MT, int NT, int OUTM>
__global__ __launch_bounds__(256) void mfma_gemm_kernel(
    const ushort_t* __restrict__ A1, const ushort_t* __restrict__ A2,
    const ushort_t* __restrict__ Wt, const float* __restrict__ bias,
    const float* __restrict__ cvals, void* __restrict__ Cout, int Nd, int Ktot)
{
    constexpr int AI = MT / 64, BI = NT / 64;
    constexpr int FI = MT / 32, FJ = NT / 32;
    __shared__ ushort_t As[2][MT * 32];
    __shared__ ushort_t Bs[2][NT * 32];
    __shared__ float mxs[64 * 2];
    __shared__ float ses[64 * 2];
    int t = threadIdx.x;
    int n0 = blockIdx.x * NT, m0 = blockIdx.y * MT;
    int wave = t >> 6, lane = t & 63;
    int wm = (wave & 1) * (MT / 2), wn = (wave >> 1) * (NT / 2);
    int lr = lane & 15, quad = lane >> 4;

    f32x4 acc[FI][FJ] = {};
    float4 aReg[AI], bReg[BI];

    auto loadAB = [&](int k0) {
        int aoff = (MODE == 2) ? ((k0 >= 1024) ? k0 - 512 : (k0 & 511)) : k0;
        int woff = (MODE == 2) ? ((k0 >= 1024) ? k0 - 1024 : k0) : k0;
        #pragma unroll
        for (int i = 0; i < AI; ++i) {
            int c = i * 256 + t, r = c >> 2, q = (c & 3) * 8;
            int gr = m0 + r;
            const ushort_t* ap;
            if (MODE == 1)      ap = (k0 < 512) ? A1 + (size_t)(gr >> 2) * 1024 + k0 + q
                                                : A2 + (size_t)gr * 512 + (k0 - 512) + q;
            else if (MODE == 2) ap = A1 + (size_t)gr * 1024 + aoff + q;
            else                ap = A1 + (size_t)gr * Ktot + k0 + q;
            aReg[i] = *(const float4*)ap;
        }
        #pragma unroll
        for (int i = 0; i < BI; ++i) {
            int c = i * 256 + t, r = c >> 2, q = (c & 3) * 8;
            size_t wstride = (MODE == 2) ? 1024 : (size_t)Ktot;
            bReg[i] = *(const float4*)(Wt + (size_t)(n0 + r) * wstride + woff + q);
        }
    };
    auto storeAB = [&](int p) {
        #pragma unroll
        for (int i = 0; i < AI; ++i) { int c = i * 256 + t; *(float4*)&As[p][c * 8] = aReg[i]; }
        #pragma unroll
        for (int i = 0; i < BI; ++i) { int c = i * 256 + t; *(float4*)&Bs[p][c * 8] = bReg[i]; }
    };

    loadAB(0);
    storeAB(0);
    int steps = Ktot >> 5;
    int p = 0;
    for (int s = 0; s < steps; ++s) {
        __syncthreads();
        if (s + 1 < steps) loadAB((s + 1) * 32);
        bf16x8 af[FI], bfr[FJ];
        #pragma unroll
        for (int i = 0; i < FI; ++i)
            af[i] = *(const bf16x8*)&As[p][(wm + i * 16 + lr) * 32 + quad * 8];
        #pragma unroll
        for (int j = 0; j < FJ; ++j)
            bfr[j] = *(const bf16x8*)&Bs[p][(wn + j * 16 + lr) * 32 + quad * 8];
        #pragma unroll
        for (int i = 0; i < FI; ++i)
            #pragma unroll
            for (int j = 0; j < FJ; ++j)
                acc[i][j] = __builtin_amdgcn_mfma_f32_16x16x32_bf16(af[i], bfr[j], acc[i][j], 0, 0, 0);
        if (s + 1 < steps) storeAB(p ^ 1);
        p ^= 1;
    }

    if (OUTM == 3) {
        float bv[FJ];
        #pragma unroll
        for (int j = 0; j < FJ; ++j) bv[j] = bias[wn + j * 16 + lr];
        int half = wave >> 1;
        float rmx[FI][4];
        #pragma unroll
        for (int i = 0; i < FI; ++i)
            #pragma unroll
            for (int r = 0; r < 4; ++r) {
                float m = -1e30f;
                #pragma unroll
                for (int j = 0; j < FJ; ++j) m = fmaxf(m, acc[i][j][r] + bv[j]);
                #pragma unroll
                for (int mk = 1; mk < 16; mk <<= 1) m = fmaxf(m, __shfl_xor(m, mk));
                if (lr == 0) mxs[(wm + i * 16 + quad * 4 + r) * 2 + half] = m;
            }
        __syncthreads();
        #pragma unroll
        for (int i = 0; i < FI; ++i)
            #pragma unroll
            for (int r = 0; r < 4; ++r) {
                int rl = wm + i * 16 + quad * 4 + r;
                rmx[i][r] = fmaxf(mxs[rl * 2], mxs[rl * 2 + 1]);
            }
        #pragma unroll
        for (int i = 0; i < FI; ++i)
            #pragma unroll
            for (int r = 0; r < 4; ++r) {
                float sv = 0.f;
                #pragma unroll
                for (int j = 0; j < FJ; ++j) sv += expf(acc[i][j][r] + bv[j] - rmx[i][r]);
                #pragma unroll
                for (int mk = 1; mk < 16; mk <<= 1) sv += __shfl_xor(sv, mk);
                if (lr == 0) ses[(wm + i * 16 + quad * 4 + r) * 2 + half] = sv;
            }
        __syncthreads();
        float* outp = (float*)Cout;
        #pragma unroll
        for (int i = 0; i < FI; ++i)
            #pragma unroll
            for (int r = 0; r < 4; ++r) {
                int rl = wm + i * 16 + quad * 4 + r;
                float se = ses[rl * 2] + ses[rl * 2 + 1];
                float addc = cvals[m0 + rl] - rmx[i][r] - logf(se);
                #pragma unroll
                for (int j = 0; j < FJ; ++j)
                    outp[(size_t)(m0 + rl) * Nd + wn + j * 16 + lr] = acc[i][j][r] + bv[j] + addc;
            }
    } else {
        #pragma unroll
        for (int j = 0; j < FJ; ++j) {
            int col = n0 + wn + j * 16 + lr;
            float bvv = bias[col];
            #pragma unroll
            for (int i = 0; i < FI; ++i) {
                #pragma unroll
                for (int r = 0; r < 4; ++r) {
                    int row = m0 + wm + i * 16 + quad * 4 + r;
                    float val = acc[i][j][r] + bvv;
                    if (OUTM == 0) {
                        ((ushort_t*)Cout)[(size_t)row * Nd + col] = f2bf(gelu_tanh(val));
                    } else if (OUTM == 1) {
                        float gv = gelu_tanh(val);
                        ushort_t h = f2bf(gv);
                        ((ushort_t*)Cout)[(size_t)row * 1024 + col] = h;
                        ((ushort_t*)Cout)[(size_t)row * 1024 + 512 + col] = f2bf(gv - bf2f(h));
                    } else {
                        ((float*)Cout)[(size_t)row * Nd + col] = val;
                    }
                }
            }
        }
    }
}

// ---------------- fused: top-4 per row + gather+LN of the 4 emb rows -> bf16 ----------------
__global__ __launch_bounds__(256) void topk_embln_kernel(Params p) {
    __shared__ int sidx[4];
    int brow = blockIdx.x, t = threadIdx.x;
    int wave = t >> 6, lane = t & 63;
    if (wave == 0) {
        const float* cr = p.coarse + (size_t)brow * N_COARSE;
        float v[4]; int id[4];
        #pragma unroll
        for (int j = 0; j < 4; ++j) { v[j] = cr[lane + 64 * j]; id[j] = lane + 64 * j; }
        #pragma unroll
        for (int r = 0; r < K_TOP; ++r) {
            float bv = v[0]; int bi = id[0];
            #pragma unroll
            for (int j = 1; j < 4; ++j)
                if (v[j] > bv || (v[j] == bv && id[j] < bi)) { bv = v[j]; bi = id[j]; }
            #pragma unroll
            for (int off = 32; off; off >>= 1) {
                float ov = __shfl_xor(bv, off); int oi = __shfl_xor(bi, off);
                if (ov > bv || (ov == bv && oi < bi)) { bv = ov; bi = oi; }
            }
            if ((bi & 63) == lane) v[bi >> 6] = -INFINITY;
            if (lane == 0) {
                sidx[r] = bi;
                p.idxb[brow * K_TOP + r] = bi;
                p.cvals[brow * K_TOP + r] = bv;
            }
        }
    }
    __syncthreads();
    int n = sidx[wave];
    const float* er = p.emb + (size_t)n * CH + lane * 8;
    float4 u0 = *(const float4*)er;
    float4 u1 = *(const float4*)(er + 4);
    float s  = u0.x + u0.y + u0.z + u0.w + u1.x + u1.y + u1.z + u1.w;
    float ss = u0.x * u0.x + u0.y * u0.y + u0.z * u0.z + u0.w * u0.w
             + u1.x * u1.x + u1.y * u1.y + u1.z * u1.z + u1.w * u1.w;
    #pragma unroll
    for (int off = 32; off; off >>= 1) { s += __shfl_xor(s, off); ss += __shfl_xor(ss, off); }
    float mean = s * (1.0f / CH);
    float var = ss * (1.0f / CH) - mean * mean;
    float rsq = rsqrtf(var + 1e-5f);
    float4 g0 = *(const float4*)(p.emb_g + lane * 8), g1 = *(const float4*)(p.emb_g + lane * 8 + 4);
    float4 b0 = *(const float4*)(p.emb_b + lane * 8), b1 = *(const float4*)(p.emb_b + lane * 8 + 4);
    uint4 pk;
    pk.x = (unsigned)f2bf((u0.x - mean) * rsq * g0.x + b0.x) |
           ((unsigned)f2bf((u0.y - mean) * rsq * g0.y + b0.y) << 16);
    pk.y = (unsigned)f2bf((u0.z - mean) * rsq * g0.z + b0.z) |
           ((unsigned)f2bf((u0.w - mean) * rsq * g0.w + b0.w) << 16);
    pk.z = (unsigned)f2bf((u1.x - mean) * rsq * g1.x + b1.x) |
           ((unsigned)f2bf((u1.y - mean) * rsq * g1.y + b1.y) << 16);
    pk.w = (unsigned)f2bf((u1.z - mean) * rsq * g1.z + b1.z) |
           ((unsigned)f2bf((u1.w - mean) * rsq * g1.w + b1.w) << 16);
    *(uint4*)(p.e_bf + (size_t)(brow * K_TOP + wave) * CH + lane * 8) = pk;
}

// ---------------- final scatter into permuted dense output ----------------
__global__ __launch_bounds__(256) void scatter_kernel(Params p) {
    const float LOG_F = 5.545177444479562f;
    int b = blockIdx.y, cx = blockIdx.x, t = threadIdx.x;
    int4 ii = *(const int4*)&p.idxb[b * 4];
    size_t rowb = (size_t)b * OUT_STRIDE + 1;
    #pragma unroll
    for (int q = 0; q < 4; ++q) {
        int o = cx * 4096 + q * 1024 + t * 4;
        int c0 = o >> 12, f0 = (o >> 8) & 15, c1 = (o >> 4) & 15, f1 = o & 15;
        int n = c0 * 16 + c1;
        int f = f0 * 16 + f1;
        int k = -1;
        if (n == ii.x) k = 0; else if (n == ii.y) k = 1; else if (n == ii.z) k = 2; else if (n == ii.w) k = 3;
        float r0, r1, r2, r3;
        if (k >= 0) {
            float4 u = *(const float4*)(p.fine + ((size_t)(b * 4 + k)) * F_FINE + f);
            r0 = u.x; r1 = u.y; r2 = u.z; r3 = u.w;
        } else {
            float base = p.coarse[(size_t)b * N_COARSE + n] - LOG_F;
            r0 = r1 = r2 = r3 = base;
        }
        float* op = p.out + rowb + o;
        __builtin_nontemporal_store(r0, op + 0);
        __builtin_nontemporal_store(r1, op + 1);
        __builtin_nontemporal_store(r2, op + 2);
        __builtin_nontemporal_store(r3, op + 3);
    }
}

extern "C" void kernel_launch(void* const* d_in, const int* in_sizes, int n_in,
                              void* d_out, int out_size, void* d_ws, size_t ws_size,
                              hipStream_t stream) {
    Params prm;
    prm.x     = (const float*)d_in[0];
    prm.in_g  = (const float*)d_in[1];
    prm.in_b  = (const float*)d_in[2];
    prm.nop_w = (const float*)d_in[3];
    prm.nop_b = (const float*)d_in[4];
    prm.c_w1  = (const float*)d_in[5];
    prm.c_b1  = (const float*)d_in[6];
    prm.c_w2  = (const float*)d_in[7];
    prm.c_b2  = (const float*)d_in[8];
    prm.c_w3  = (const float*)d_in[9];
    prm.c_b3  = (const float*)d_in[10];
    prm.emb   = (const float*)d_in[11];
    prm.emb_g = (const float*)d_in[12];
    prm.emb_b = (const float*)d_in[13];
    prm.f_w1  = (const float*)d_in[14];
    prm.f_b1  = (const float*)d_in[15];
    prm.f_w2  = (const float*)d_in[16];
    prm.f_b2  = (const float*)d_in[17];
    prm.f_w3  = (const float*)d_in[18];
    prm.f_b3  = (const float*)d_in[19];

    float* ws = (float*)d_ws;
    prm.coarse  = ws;                             // 2048*256 f32
    prm.fine    = prm.coarse + 524288;            // 8192*256 f32
    prm.xnsp    = (ushort_t*)(prm.fine + 2097152);  // 2048*1024 bf16 [hi|lo]
    prm.h1sp    = prm.xnsp + 2097152;             // 2048*1024
    prm.h2sp    = prm.h1sp + 2097152;             // 2048*1024
    prm.e_bf    = prm.h2sp + 2097152;             // 8192*512
    prm.fh1_bf  = prm.e_bf + 4194304;             // 8192*512
    prm.fh2_bf  = prm.fh1_bf + 4194304;           // 8192*512
    prm.wt1     = prm.fh2_bf + 4194304;           // 512*1024
    prm.wt2     = prm.wt1 + 524288;               // 512*512
    prm.wt3     = prm.wt2 + 262144;               // 256*512
    prm.cwt1    = prm.wt3 + 131072;               // 512*1024
    prm.cwt2    = prm.cwt1 + 524288;              // 512*1024
    prm.cwt3    = prm.cwt2 + 524288;              // 256*1024
    prm.idxb    = (int*)(prm.cwt3 + 262144);      // 8192
    prm.cvals   = (float*)(prm.idxb + 8192);      // 8192
    prm.out     = (float*)d_out;

    // 1. fused prep: fine convT + coarse convT hi/lo + LN+no_op
    prep_kernel<<<3584, 256, 0, stream>>>(prm);
    // 2-4. coarse MLP via 3-term split-bf16 MFMA (K=1536)
    mfma_gemm_kernel<2, 64, 64, 1><<<dim3(8, 32), 256, 0, stream>>>(
        prm.xnsp, nullptr, prm.cwt1, prm.c_b1, nullptr, prm.h1sp, 512, 1536);
    mfma_gemm_kernel<2, 64, 64, 1><<<dim3(8, 32), 256, 0, stream>>>(
        prm.h1sp, nullptr, prm.cwt2, prm.c_b2, nullptr, prm.h2sp, 512, 1536);
    mfma_gemm_kernel<2, 64, 64, 2><<<dim3(4, 32), 256, 0, stream>>>(
        prm.h2sp, nullptr, prm.cwt3, prm.c_b3, nullptr, prm.coarse, 256, 1536);
    // 5. fused top-4 + emb gather+LN -> bf16
    topk_embln_kernel<<<BATCH, 256, 0, stream>>>(prm);
    // 6. fh1 = gelu(concat(xn_hi, e) @ f_w1 + f_b1)   64x64 tiles, 1024 blocks (4/CU)
    mfma_gemm_kernel<1, 64, 64, 0><<<dim3(8, 128), 256, 0, stream>>>(
        prm.xnsp, prm.e_bf, prm.wt1, prm.f_b1, nullptr, prm.fh1_bf, 512, 1024);
    // 7. fh2 = gelu(fh1 @ f_w2 + f_b2)   64x64 tiles, 1024 blocks
    mfma_gemm_kernel<0, 64, 64, 0><<<dim3(8, 128), 256, 0, stream>>>(
        prm.fh1_bf, nullptr, prm.wt2, prm.f_b2, nullptr, prm.fh2_bf, 512, 512);
    // 8. fine = cvals + log_softmax(fh2 @ f_w3 + f_b3)
    mfma_gemm_kernel<0, 64, 256, 3><<<dim3(1, 128), 256, 0, stream>>>(
        prm.fh2_bf, nullptr, prm.wt3, prm.f_b3, prm.cvals, prm.fine, 256, 512);
    // 9. scatter to permuted output (wide launch, write-BW bound)
    scatter_kernel<<<dim3(16, BATCH), 256, 0, stream>>>(prm);
}

// Round 14
// 729.646 us; speedup vs baseline: 1.6163x; 1.0005x over previous
//
#include <hip/hip_runtime.h>
#include <math.h>

#define BATCH 2048
#define CH 512
#define N_COARSE 256
#define F_FINE 256
#define K_TOP 4
#define OUT_STRIDE 65537  // 1 + N*F

typedef unsigned short ushort_t;
typedef __bf16 bf16x8 __attribute__((ext_vector_type(8)));
typedef float f32x4 __attribute__((ext_vector_type(4)));

__device__ __forceinline__ float gelu_tanh(float x) {
    float x3 = x * x * x;
    float t = tanhf(0.7978845608028654f * (x + 0.044715f * x3));
    return 0.5f * x * (1.0f + t);
}

__device__ __forceinline__ ushort_t f2bf(float f) {
    unsigned u = __float_as_uint(f);
    unsigned r = (u + 0x7FFF + ((u >> 16) & 1)) >> 16;
    return (ushort_t)r;
}
__device__ __forceinline__ float bf2f(ushort_t h) {
    return __uint_as_float(((unsigned)h) << 16);
}

struct Params {
    const float *x, *in_g, *in_b, *nop_w, *nop_b;
    const float *c_w1, *c_b1, *c_w2, *c_b2, *c_w3, *c_b3;
    const float *emb, *emb_g, *emb_b;
    const float *f_w1, *f_b1, *f_w2, *f_b2, *f_w3, *f_b3;
    float *coarse, *fine, *out, *cvals;
    ushort_t *xnsp, *h1sp, *h2sp, *e_bf, *fh1_bf, *fh2_bf;
    ushort_t *wt1, *wt2, *wt3, *cwt1, *cwt2, *cwt3;
    int *idxb;
};

// ---------------- prep: u<896 fine convT; u<1536 coarse convT hi/lo; else LN+no_op ----
__global__ __launch_bounds__(256) void prep_kernel(Params p) {
    __shared__ float s[32][33];
    int u = blockIdx.x, t = threadIdx.x;
    if (u < 1536) {
        const float* W; ushort_t* Wt; int Kd, Nd, gx, gy; bool split;
        if (u < 512)       { W=p.f_w1; Wt=p.wt1; Kd=1024; Nd=512; gx=u&15; gy=u>>4; split=false; }
        else if (u < 768)  { int v=u-512;  W=p.f_w2; Wt=p.wt2; Kd=512; Nd=512; gx=v&15; gy=v>>4; split=false; }
        else if (u < 896)  { int v=u-768;  W=p.f_w3; Wt=p.wt3; Kd=512; Nd=256; gx=v&7;  gy=v>>3; split=false; }
        else if (u < 1152) { int v=u-896;  W=p.c_w1; Wt=p.cwt1; Kd=512; Nd=512; gx=v&15; gy=v>>4; split=true; }
        else if (u < 1408) { int v=u-1152; W=p.c_w2; Wt=p.cwt2; Kd=512; Nd=512; gx=v&15; gy=v>>4; split=true; }
        else               { int v=u-1408; W=p.c_w3; Wt=p.cwt3; Kd=512; Nd=256; gx=v&7;  gy=v>>3; split=true; }
        int tx = t & 31, ty = t >> 5;
        int n0 = gx * 32, k0 = gy * 32;
        #pragma unroll
        for (int i = 0; i < 4; ++i) {
            int r = ty + i * 8;
            s[r][tx] = W[(size_t)(k0 + r) * Nd + n0 + tx];
        }
        __syncthreads();
        if (!split) {
            #pragma unroll
            for (int i = 0; i < 4; ++i) {
                int r = ty + i * 8;
                Wt[(size_t)(n0 + r) * Kd + k0 + tx] = f2bf(s[tx][r]);
            }
        } else {
            #pragma unroll
            for (int i = 0; i < 4; ++i) {
                int r = ty + i * 8;
                float v = s[tx][r];
                ushort_t h = f2bf(v);
                Wt[(size_t)(n0 + r) * 1024 + k0 + tx] = h;
                Wt[(size_t)(n0 + r) * 1024 + 512 + k0 + tx] = f2bf(v - bf2f(h));
            }
        }
    } else {
        float* red = &s[0][0];
        int row = u - 1536;
        int lane = t & 63, wave = t >> 6;
        const float* xr = p.x + (size_t)row * CH;
        float v0 = xr[t], v1 = xr[t + 256];
        float sm = v0 + v1, ss = v0 * v0 + v1 * v1;
        #pragma unroll
        for (int off = 32; off; off >>= 1) { sm += __shfl_xor(sm, off); ss += __shfl_xor(ss, off); }
        if (lane == 0) { red[wave] = sm; red[4 + wave] = ss; }
        __syncthreads();
        sm = red[0] + red[1] + red[2] + red[3];
        ss = red[4] + red[5] + red[6] + red[7];
        float mean = sm * (1.0f / CH);
        float var = ss * (1.0f / CH) - mean * mean;
        float rsq = rsqrtf(var + 1e-5f);
        float xn0 = (v0 - mean) * rsq * p.in_g[t] + p.in_b[t];
        float xn1 = (v1 - mean) * rsq * p.in_g[t + 256] + p.in_b[t + 256];
        ushort_t* xr2 = p.xnsp + (size_t)row * 1024;
        ushort_t h0 = f2bf(xn0), h1v = f2bf(xn1);
        xr2[t] = h0; xr2[t + 256] = h1v;
        xr2[512 + t] = f2bf(xn0 - bf2f(h0));
        xr2[512 + t + 256] = f2bf(xn1 - bf2f(h1v));
        float d = xn0 * p.nop_w[t] + xn1 * p.nop_w[t + 256];
        #pragma unroll
        for (int off = 32; off; off >>= 1) d += __shfl_xor(d, off);
        __syncthreads();
        if (lane == 0) red[wave] = d;
        __syncthreads();
        if (t == 0) p.out[(size_t)row * OUT_STRIDE] = red[0] + red[1] + red[2] + red[3] + p.nop_b[0];
    }
}

// ---------------- bf16 MFMA GEMM, MTxNT tile, BK=32, reg-prefetch + LDS dbuf ----------------
// MODE 0: A1 row-major stride Ktot.  MODE 1: concat hi(xnsp)/e.  MODE 2: 3-term split K=1536.
// OUTM 0: bf16+gelu stride Nd. OUTM 1: split hi/lo bf16+gelu stride 1024.
// OUTM 2: f32. OUTM 3: f32 = cvals + log_softmax (NT==Nd==256, MT==64).
template<int MODE, int MT, int NT, int OUTM>
__global__ __launch_bounds__(256) void mfma_gemm_kernel(
    const ushort_t* __restrict__ A1, const ushort_t* __restrict__ A2,
    const ushort_t* __restrict__ Wt, const float* __restrict__ bias,
    const float* __restrict__ cvals, void* __restrict__ Cout, int Nd, int Ktot)
{
    constexpr int AI = MT / 64, BI = NT / 64;
    constexpr int FI = MT / 32, FJ = NT / 32;
    __shared__ ushort_t As[2][MT * 32];
    __shared__ ushort_t Bs[2][NT * 32];
    __shared__ float mxs[64 * 2];
    __shared__ float ses[64 * 2];
    int t = threadIdx.x;
    int n0 = blockIdx.x * NT, m0 = blockIdx.y * MT;
    int wave = t >> 6, lane = t & 63;
    int wm = (wave & 1) * (MT / 2), wn = (wave >> 1) * (NT / 2);
    int lr = lane & 15, quad = lane >> 4;

    f32x4 acc[FI][FJ] = {};
    float4 aReg[AI], bReg[BI];

    auto loadAB = [&](int k0) {
        int aoff = (MODE == 2) ? ((k0 >= 1024) ? k0 - 512 : (k0 & 511)) : k0;
        int woff = (MODE == 2) ? ((k0 >= 1024) ? k0 - 1024 : k0) : k0;
        #pragma unroll
        for (int i = 0; i < AI; ++i) {
            int c = i * 256 + t, r = c >> 2, q = (c & 3) * 8;
            int gr = m0 + r;
            const ushort_t* ap;
            if (MODE == 1)      ap = (k0 < 512) ? A1 + (size_t)(gr >> 2) * 1024 + k0 + q
                                                : A2 + (size_t)gr * 512 + (k0 - 512) + q;
            else if (MODE == 2) ap = A1 + (size_t)gr * 1024 + aoff + q;
            else                ap = A1 + (size_t)gr * Ktot + k0 + q;
            aReg[i] = *(const float4*)ap;
        }
        #pragma unroll
        for (int i = 0; i < BI; ++i) {
            int c = i * 256 + t, r = c >> 2, q = (c & 3) * 8;
            size_t wstride = (MODE == 2) ? 1024 : (size_t)Ktot;
            bReg[i] = *(const float4*)(Wt + (size_t)(n0 + r) * wstride + woff + q);
        }
    };
    auto storeAB = [&](int p) {
        #pragma unroll
        for (int i = 0; i < AI; ++i) { int c = i * 256 + t; *(float4*)&As[p][c * 8] = aReg[i]; }
        #pragma unroll
        for (int i = 0; i < BI; ++i) { int c = i * 256 + t; *(float4*)&Bs[p][c * 8] = bReg[i]; }
    };

    loadAB(0);
    storeAB(0);
    int steps = Ktot >> 5;
    int p = 0;
    for (int s = 0; s < steps; ++s) {
        __syncthreads();
        if (s + 1 < steps) loadAB((s + 1) * 32);
        bf16x8 af[FI], bfr[FJ];
        #pragma unroll
        for (int i = 0; i < FI; ++i)
            af[i] = *(const bf16x8*)&As[p][(wm + i * 16 + lr) * 32 + quad * 8];
        #pragma unroll
        for (int j = 0; j < FJ; ++j)
            bfr[j] = *(const bf16x8*)&Bs[p][(wn + j * 16 + lr) * 32 + quad * 8];
        #pragma unroll
        for (int i = 0; i < FI; ++i)
            #pragma unroll
            for (int j = 0; j < FJ; ++j)
                acc[i][j] = __builtin_amdgcn_mfma_f32_16x16x32_bf16(af[i], bfr[j], acc[i][j], 0, 0, 0);
        if (s + 1 < steps) storeAB(p ^ 1);
        p ^= 1;
    }

    if (OUTM == 3) {
        float bv[FJ];
        #pragma unroll
        for (int j = 0; j < FJ; ++j) bv[j] = bias[wn + j * 16 + lr];
        int half = wave >> 1;
        float rmx[FI][4];
        #pragma unroll
        for (int i = 0; i < FI; ++i)
            #pragma unroll
            for (int r = 0; r < 4; ++r) {
                float m = -1e30f;
                #pragma unroll
                for (int j = 0; j < FJ; ++j) m = fmaxf(m, acc[i][j][r] + bv[j]);
                #pragma unroll
                for (int mk = 1; mk < 16; mk <<= 1) m = fmaxf(m, __shfl_xor(m, mk));
                if (lr == 0) mxs[(wm + i * 16 + quad * 4 + r) * 2 + half] = m;
            }
        __syncthreads();
        #pragma unroll
        for (int i = 0; i < FI; ++i)
            #pragma unroll
            for (int r = 0; r < 4; ++r) {
                int rl = wm + i * 16 + quad * 4 + r;
                rmx[i][r] = fmaxf(mxs[rl * 2], mxs[rl * 2 + 1]);
            }
        #pragma unroll
        for (int i = 0; i < FI; ++i)
            #pragma unroll
            for (int r = 0; r < 4; ++r) {
                float sv = 0.f;
                #pragma unroll
                for (int j = 0; j < FJ; ++j) sv += expf(acc[i][j][r] + bv[j] - rmx[i][r]);
                #pragma unroll
                for (int mk = 1; mk < 16; mk <<= 1) sv += __shfl_xor(sv, mk);
                if (lr == 0) ses[(wm + i * 16 + quad * 4 + r) * 2 + half] = sv;
            }
        __syncthreads();
        float* outp = (float*)Cout;
        #pragma unroll
        for (int i = 0; i < FI; ++i)
            #pragma unroll
            for (int r = 0; r < 4; ++r) {
                int rl = wm + i * 16 + quad * 4 + r;
                float se = ses[rl * 2] + ses[rl * 2 + 1];
                float addc = cvals[m0 + rl] - rmx[i][r] - logf(se);
                #pragma unroll
                for (int j = 0; j < FJ; ++j)
                    outp[(size_t)(m0 + rl) * Nd + wn + j * 16 + lr] = acc[i][j][r] + bv[j] + addc;
            }
    } else {
        #pragma unroll
        for (int j = 0; j < FJ; ++j) {
            int col = n0 + wn + j * 16 + lr;
            float bvv = bias[col];
            #pragma unroll
            for (int i = 0; i < FI; ++i) {
                #pragma unroll
                for (int r = 0; r < 4; ++r) {
                    int row = m0 + wm + i * 16 + quad * 4 + r;
                    float val = acc[i][j][r] + bvv;
                    if (OUTM == 0) {
                        ((ushort_t*)Cout)[(size_t)row * Nd + col] = f2bf(gelu_tanh(val));
                    } else if (OUTM == 1) {
                        float gv = gelu_tanh(val);
                        ushort_t h = f2bf(gv);
                        ((ushort_t*)Cout)[(size_t)row * 1024 + col] = h;
                        ((ushort_t*)Cout)[(size_t)row * 1024 + 512 + col] = f2bf(gv - bf2f(h));
                    } else {
                        ((float*)Cout)[(size_t)row * Nd + col] = val;
                    }
                }
            }
        }
    }
}

// ---------------- fused: top-4 per row + gather+LN of the 4 emb rows -> bf16 ----------------
__global__ __launch_bounds__(256) void topk_embln_kernel(Params p) {
    __shared__ int sidx[4];
    int brow = blockIdx.x, t = threadIdx.x;
    int wave = t >> 6, lane = t & 63;
    if (wave == 0) {
        const float* cr = p.coarse + (size_t)brow * N_COARSE;
        float v[4]; int id[4];
        #pragma unroll
        for (int j = 0; j < 4; ++j) { v[j] = cr[lane + 64 * j]; id[j] = lane + 64 * j; }
        #pragma unroll
        for (int r = 0; r < K_TOP; ++r) {
            float bv = v[0]; int bi = id[0];
            #pragma unroll
            for (int j = 1; j < 4; ++j)
                if (v[j] > bv || (v[j] == bv && id[j] < bi)) { bv = v[j]; bi = id[j]; }
            #pragma unroll
            for (int off = 32; off; off >>= 1) {
                float ov = __shfl_xor(bv, off); int oi = __shfl_xor(bi, off);
                if (ov > bv || (ov == bv && oi < bi)) { bv = ov; bi = oi; }
            }
            if ((bi & 63) == lane) v[bi >> 6] = -INFINITY;
            if (lane == 0) {
                sidx[r] = bi;
                p.idxb[brow * K_TOP + r] = bi;
                p.cvals[brow * K_TOP + r] = bv;
            }
        }
    }
    __syncthreads();
    int n = sidx[wave];
    const float* er = p.emb + (size_t)n * CH + lane * 8;
    float4 u0 = *(const float4*)er;
    float4 u1 = *(const float4*)(er + 4);
    float s  = u0.x + u0.y + u0.z + u0.w + u1.x + u1.y + u1.z + u1.w;
    float ss = u0.x * u0.x + u0.y * u0.y + u0.z * u0.z + u0.w * u0.w
             + u1.x * u1.x + u1.y * u1.y + u1.z * u1.z + u1.w * u1.w;
    #pragma unroll
    for (int off = 32; off; off >>= 1) { s += __shfl_xor(s, off); ss += __shfl_xor(ss, off); }
    float mean = s * (1.0f / CH);
    float var = ss * (1.0f / CH) - mean * mean;
    float rsq = rsqrtf(var + 1e-5f);
    float4 g0 = *(const float4*)(p.emb_g + lane * 8), g1 = *(const float4*)(p.emb_g + lane * 8 + 4);
    float4 b0 = *(const float4*)(p.emb_b + lane * 8), b1 = *(const float4*)(p.emb_b + lane * 8 + 4);
    uint4 pk;
    pk.x = (unsigned)f2bf((u0.x - mean) * rsq * g0.x + b0.x) |
           ((unsigned)f2bf((u0.y - mean) * rsq * g0.y + b0.y) << 16);
    pk.y = (unsigned)f2bf((u0.z - mean) * rsq * g0.z + b0.z) |
           ((unsigned)f2bf((u0.w - mean) * rsq * g0.w + b0.w) << 16);
    pk.z = (unsigned)f2bf((u1.x - mean) * rsq * g1.x + b1.x) |
           ((unsigned)f2bf((u1.y - mean) * rsq * g1.y + b1.y) << 16);
    pk.w = (unsigned)f2bf((u1.z - mean) * rsq * g1.z + b1.z) |
           ((unsigned)f2bf((u1.w - mean) * rsq * g1.w + b1.w) << 16);
    *(uint4*)(p.e_bf + (size_t)(brow * K_TOP + wave) * CH + lane * 8) = pk;
}

// ---------------- final scatter into permuted dense output ----------------
__global__ __launch_bounds__(256) void scatter_kernel(Params p) {
    const float LOG_F = 5.545177444479562f;
    int b = blockIdx.y, cx = blockIdx.x, t = threadIdx.x;
    int4 ii = *(const int4*)&p.idxb[b * 4];
    size_t rowb = (size_t)b * OUT_STRIDE + 1;
    #pragma unroll
    for (int q = 0; q < 4; ++q) {
        int o = cx * 4096 + q * 1024 + t * 4;
        int c0 = o >> 12, f0 = (o >> 8) & 15, c1 = (o >> 4) & 15, f1 = o & 15;
        int n = c0 * 16 + c1;
        int f = f0 * 16 + f1;
        int k = -1;
        if (n == ii.x) k = 0; else if (n == ii.y) k = 1; else if (n == ii.z) k = 2; else if (n == ii.w) k = 3;
        float r0, r1, r2, r3;
        if (k >= 0) {
            float4 u = *(const float4*)(p.fine + ((size_t)(b * 4 + k)) * F_FINE + f);
            r0 = u.x; r1 = u.y; r2 = u.z; r3 = u.w;
        } else {
            float base = p.coarse[(size_t)b * N_COARSE + n] - LOG_F;
            r0 = r1 = r2 = r3 = base;
        }
        float* op = p.out + rowb + o;
        __builtin_nontemporal_store(r0, op + 0);
        __builtin_nontemporal_store(r1, op + 1);
        __builtin_nontemporal_store(r2, op + 2);
        __builtin_nontemporal_store(r3, op + 3);
    }
}

extern "C" void kernel_launch(void* const* d_in, const int* in_sizes, int n_in,
                              void* d_out, int out_size, void* d_ws, size_t ws_size,
                              hipStream_t stream) {
    Params prm;
    prm.x     = (const float*)d_in[0];
    prm.in_g  = (const float*)d_in[1];
    prm.in_b  = (const float*)d_in[2];
    prm.nop_w = (const float*)d_in[3];
    prm.nop_b = (const float*)d_in[4];
    prm.c_w1  = (const float*)d_in[5];
    prm.c_b1  = (const float*)d_in[6];
    prm.c_w2  = (const float*)d_in[7];
    prm.c_b2  = (const float*)d_in[8];
    prm.c_w3  = (const float*)d_in[9];
    prm.c_b3  = (const float*)d_in[10];
    prm.emb   = (const float*)d_in[11];
    prm.emb_g = (const float*)d_in[12];
    prm.emb_b = (const float*)d_in[13];
    prm.f_w1  = (const float*)d_in[14];
    prm.f_b1  = (const float*)d_in[15];
    prm.f_w2  = (const float*)d_in[16];
    prm.f_b2  = (const float*)d_in[17];
    prm.f_w3  = (const float*)d_in[18];
    prm.f_b3  = (const float*)d_in[19];

    float* ws = (float*)d_ws;
    prm.coarse  = ws;                             // 2048*256 f32
    prm.fine    = prm.coarse + 524288;            // 8192*256 f32
    prm.xnsp    = (ushort_t*)(prm.fine + 2097152);  // 2048*1024 bf16 [hi|lo]
    prm.h1sp    = prm.xnsp + 2097152;             // 2048*1024
    prm.h2sp    = prm.h1sp + 2097152;             // 2048*1024
    prm.e_bf    = prm.h2sp + 2097152;             // 8192*512
    prm.fh1_bf  = prm.e_bf + 4194304;             // 8192*512
    prm.fh2_bf  = prm.fh1_bf + 4194304;           // 8192*512
    prm.wt1     = prm.fh2_bf + 4194304;           // 512*1024
    prm.wt2     = prm.wt1 + 524288;               // 512*512
    prm.wt3     = prm.wt2 + 262144;               // 256*512
    prm.cwt1    = prm.wt3 + 131072;               // 512*1024
    prm.cwt2    = prm.cwt1 + 524288;              // 512*1024
    prm.cwt3    = prm.cwt2 + 524288;              // 256*1024
    prm.idxb    = (int*)(prm.cwt3 + 262144);      // 8192
    prm.cvals   = (float*)(prm.idxb + 8192);      // 8192
    prm.out     = (float*)d_out;

    // 1. fused prep: fine convT + coarse convT hi/lo + LN+no_op
    prep_kernel<<<3584, 256, 0, stream>>>(prm);
    // 2-4. coarse MLP via 3-term split-bf16 MFMA (K=1536)
    mfma_gemm_kernel<2, 64, 64, 1><<<dim3(8, 32), 256, 0, stream>>>(
        prm.xnsp, nullptr, prm.cwt1, prm.c_b1, nullptr, prm.h1sp, 512, 1536);
    mfma_gemm_kernel<2, 64, 64, 1><<<dim3(8, 32), 256, 0, stream>>>(
        prm.h1sp, nullptr, prm.cwt2, prm.c_b2, nullptr, prm.h2sp, 512, 1536);
    mfma_gemm_kernel<2, 64, 64, 2><<<dim3(4, 32), 256, 0, stream>>>(
        prm.h2sp, nullptr, prm.cwt3, prm.c_b3, nullptr, prm.coarse, 256, 1536);
    // 5. fused top-4 + emb gather+LN -> bf16
    topk_embln_kernel<<<BATCH, 256, 0, stream>>>(prm);
    // 6. fh1 = gelu(concat(xn_hi, e) @ f_w1 + f_b1)   64x64 tiles, 1024 blocks (4/CU)
    mfma_gemm_kernel<1, 64, 64, 0><<<dim3(8, 128), 256, 0, stream>>>(
        prm.xnsp, prm.e_bf, prm.wt1, prm.f_b1, nullptr, prm.fh1_bf, 512, 1024);
    // 7. fh2 = gelu(fh1 @ f_w2 + f_b2)   64x64 tiles, 1024 blocks
    mfma_gemm_kernel<0, 64, 64, 0><<<dim3(8, 128), 256, 0, stream>>>(
        prm.fh1_bf, nullptr, prm.wt2, prm.f_b2, nullptr, prm.fh2_bf, 512, 512);
    // 8. fine = cvals + log_softmax(fh2 @ f_w3 + f_b3)
    mfma_gemm_kernel<0, 64, 256, 3><<<dim3(1, 128), 256, 0, stream>>>(
        prm.fh2_bf, nullptr, prm.wt3, prm.f_b3, prm.cvals, prm.fine, 256, 512);
    // 9. scatter to permuted output (wide launch, write-BW bound)
    scatter_kernel<<<dim3(16, BATCH), 256, 0, stream>>>(prm);
}